// Round 2
// baseline (2701.647 us; speedup 1.0000x reference)
//
#include <hip/hip_runtime.h>
#include <hip/hip_cooperative_groups.h>

namespace cg = cooperative_groups;

typedef unsigned short ushort_t;
typedef __attribute__((ext_vector_type(8))) short short8;
typedef __attribute__((ext_vector_type(4))) float floatx4;
typedef __attribute__((ext_vector_type(4))) ushort_t us4;

#define WAIT_VM0() __builtin_amdgcn_s_waitcnt(0x0F70)
#define WAIT_VM2() __builtin_amdgcn_s_waitcnt(0x0F72)
#define WAIT_VM4() __builtin_amdgcn_s_waitcnt(0x0F74)
#define BAR() __builtin_amdgcn_s_barrier()

__device__ __forceinline__ ushort_t f2bf(float f) {
  union { float f; unsigned u; } v; v.f = f;
  unsigned r = v.u + 0x7fffu + ((v.u >> 16) & 1u);
  return (ushort_t)(r >> 16);
}
__device__ __forceinline__ float fast_sigmoid(float x) {
  return 1.f / (1.f + __expf(-x));
}
__device__ __forceinline__ float fast_tanh(float x) {
  return 1.f - 2.f / (__expf(2.f * x) + 1.f);
}

__device__ __forceinline__ void gld16(const void* g, void* l) {
  __builtin_amdgcn_global_load_lds(
      (__attribute__((address_space(1))) void*)g,
      (__attribute__((address_space(3))) void*)l, 16, 0, 0);
}

// Stage a 64(rows)x64(k) bf16 chunk from row-major src (leading dim ldk) into
// a 8KB LDS chunk laid out as: seq chunk c (16B) holds (r=c>>3, slot s=c&7),
// global k-chunk = s ^ (r&7). 2 gld16 per thread.
__device__ __forceinline__ void stage64(const ushort_t* src, int ldk,
                                        short* dst, int w, int l) {
  int r0 = (w << 3) + (l >> 3);
  int cb0 = (l & 7) ^ (r0 & 7);
  int r1 = 32 + r0;
  int cb1 = (l & 7) ^ (r1 & 7);
  gld16(src + (size_t)r0 * ldk + (cb0 << 3), dst + (w << 9));
  gld16(src + (size_t)r1 * ldk + (cb1 << 3), dst + 2048 + (w << 9));
}

// One BK=64 chunk of MFMA. A from 64-wide staged chunk; B from LDS with
// leading dim bld (64 = staged chunk, 1024 = resident slab) at k-offset bko.
__device__ __forceinline__ void compute_chunk(const short* As, const short* Bs,
                                              int bld, int bko,
                                              floatx4 acc[2][2], int wm, int wn,
                                              int lhi, int llo) {
#pragma unroll
  for (int ks = 0; ks < 2; ++ks) {
    short8 a[2], b[2];
#pragma unroll
    for (int tm = 0; tm < 2; ++tm) {
      int m = (wm << 5) + (tm << 4) + llo;
      int ph = ((ks << 2) + lhi) ^ (m & 7);
      a[tm] = *(const short8*)(As + m * 64 + (ph << 3));
    }
#pragma unroll
    for (int tn = 0; tn < 2; ++tn) {
      int n = (wn << 5) + (tn << 4) + llo;
      int ph = ((ks << 2) + lhi) ^ (n & 7);
      b[tn] = *(const short8*)(Bs + n * bld + bko + (ph << 3));
    }
#pragma unroll
    for (int tm = 0; tm < 2; ++tm)
#pragma unroll
      for (int tn = 0; tn < 2; ++tn)
        acc[tm][tn] = __builtin_amdgcn_mfma_f32_16x16x32_bf16(
            a[tm], b[tn], acc[tm][tn], 0, 0, 0);
  }
}

__device__ __forceinline__ void epilogue(floatx4 acc[2][2], const float* bias,
                                         const float* extra, ushort_t* outb,
                                         float* outf, const float* Wa,
                                         float* pacc, int step, int act, int m0,
                                         int n0, int wm, int wn, int lhi,
                                         int llo) {
  float hv[2][2][4];
#pragma unroll
  for (int tm = 0; tm < 2; ++tm)
#pragma unroll
    for (int tn = 0; tn < 2; ++tn)
#pragma unroll
      for (int i = 0; i < 4; ++i) {
        int gm = m0 + (wm << 5) + (tm << 4) + (lhi << 2) + i;
        int gn = n0 + (wn << 5) + (tn << 4) + llo;
        float v = acc[tm][tn][i];
        if (bias) v += bias[gn];
        if (extra) v += extra[((size_t)gm << 10) + gn];
        if (act == 0) v = fmaxf(v, 0.f);
        else if (act == 1) v = fast_tanh(v);
        if (outb) outb[((size_t)gm << 10) + gn] = f2bf(v);
        if (outf) outf[((size_t)gm << 10) + gn] = v;
        hv[tm][tn][i] = v;
      }
  if (pacc) {
#pragma unroll
    for (int tm = 0; tm < 2; ++tm)
#pragma unroll
      for (int i = 0; i < 4; ++i) {
        float s = 0.f;
#pragma unroll
        for (int tn = 0; tn < 2; ++tn)
          s += hv[tm][tn][i] * Wa[n0 + (wn << 5) + (tn << 4) + llo];
        s += __shfl_xor(s, 1);
        s += __shfl_xor(s, 2);
        s += __shfl_xor(s, 4);
        s += __shfl_xor(s, 8);
        if (llo == 0)
          atomicAdd(&pacc[step * 1024 + m0 + (wm << 5) + (tm << 4) + (lhi << 2) + i], s);
      }
  }
}

// Streamed-B GEMM used for the 3 feed-forward GEMMs (before slab residency).
// Double-buffers both A and B chunks in lds[0..32K).
__device__ void gemm_stream(const ushort_t* A, const ushort_t* W, int K,
                            const float* bias, ushort_t* outb, float* outf,
                            int act, char* lds, int w, int l, int wm, int wn,
                            int lhi, int llo, int m0, int n0) {
  short* Ab[2] = {(short*)lds, (short*)(lds + 8192)};
  short* Bb[2] = {(short*)(lds + 16384), (short*)(lds + 24576)};
  floatx4 acc[2][2];
#pragma unroll
  for (int i = 0; i < 2; ++i)
#pragma unroll
    for (int j = 0; j < 2; ++j) acc[i][j] = (floatx4){0.f, 0.f, 0.f, 0.f};
  const ushort_t* Abase = A + (size_t)m0 * K;
  const ushort_t* Bbase = W + (size_t)n0 * K;
  int nc = K >> 6;
  stage64(Abase, K, Ab[0], w, l);
  stage64(Bbase, K, Bb[0], w, l);
  for (int c = 0; c < nc; ++c) {
    if (c + 1 < nc) {
      stage64(Abase + ((c + 1) << 6), K, Ab[(c + 1) & 1], w, l);
      stage64(Bbase + ((c + 1) << 6), K, Bb[(c + 1) & 1], w, l);
      WAIT_VM4();  // chunk c's 4 glds done; c+1's still in flight
    } else {
      WAIT_VM0();
    }
    BAR();
    compute_chunk(Ab[c & 1], Bb[c & 1], 64, 0, acc, wm, wn, lhi, llo);
    BAR();
  }
  epilogue(acc, bias, nullptr, outb, outf, nullptr, nullptr, 0, act, m0, n0,
           wm, wn, lhi, llo);
}

struct KP {
  const float *x, *W1, *b1, *W2, *b2, *Wih, *Whh, *bih, *bhh, *Wa, *ba;
  ushort_t *Xb, *W1b, *W2b, *Wihb, *Whhb, *Wsmb, *X1b, *Xlb, *Hb0, *Hb1;
  float *xw, *bias, *pacc, *probs, *hxout;
};

__global__ __launch_bounds__(256, 1) void fused_rnn(KP p) {
  extern __shared__ char lds[];
  cg::grid_group grid = cg::this_grid();
  const int t = threadIdx.x;
  const int w = t >> 6, l = t & 63;
  const int wm = w >> 1, wn = w & 1;
  const int lhi = l >> 4, llo = l & 15;
  const int bid = blockIdx.x;
  const int m0 = (bid >> 4) << 6, n0 = (bid & 15) << 6;
  const int gid = bid * 256 + t;

  // ---- phase 0: fp32->bf16 casts, Wsum, bias, pacc zero ----
  {
    const float4* xf = (const float4*)p.x;
    const float4* w1f = (const float4*)p.W1;
    const float4* w2f = (const float4*)p.W2;
    const float4* wif = (const float4*)p.Wih;
    const float4* whf = (const float4*)p.Whh;
    for (int i = gid; i < 1048576; i += 65536) {
      float4 v = xf[i];
      us4 o;
      o.x = f2bf(v.x); o.y = f2bf(v.y); o.z = f2bf(v.z); o.w = f2bf(v.w);
      ((us4*)p.Xb)[i] = o;
      float4 u = w1f[i];
      o.x = f2bf(u.x); o.y = f2bf(u.y); o.z = f2bf(u.z); o.w = f2bf(u.w);
      ((us4*)p.W1b)[i] = o;
      if (i < 262144) {
        float4 a = w2f[i];
        o.x = f2bf(a.x); o.y = f2bf(a.y); o.z = f2bf(a.z); o.w = f2bf(a.w);
        ((us4*)p.W2b)[i] = o;
        float4 pp = wif[i];
        o.x = f2bf(pp.x); o.y = f2bf(pp.y); o.z = f2bf(pp.z); o.w = f2bf(pp.w);
        ((us4*)p.Wihb)[i] = o;
        float4 q = whf[i];
        o.x = f2bf(q.x); o.y = f2bf(q.y); o.z = f2bf(q.z); o.w = f2bf(q.w);
        ((us4*)p.Whhb)[i] = o;
        o.x = f2bf(pp.x + q.x); o.y = f2bf(pp.y + q.y);
        o.z = f2bf(pp.z + q.z); o.w = f2bf(pp.w + q.w);
        ((us4*)p.Wsmb)[i] = o;
      }
    }
    p.pacc[gid] = 0.f;
    if (gid < 1024) p.bias[gid] = p.bih[gid] + p.bhh[gid];
  }
  grid.sync();

  // ---- phases 1-3: X1 = relu(x@W1^T+b1); x_low = relu(X1@W2^T+b2);
  //                  xw = x_low@Wih^T (fp32) ----
  gemm_stream(p.Xb, p.W1b, 4096, p.b1, p.X1b, nullptr, 0, lds, w, l, wm, wn,
              lhi, llo, m0, n0);
  grid.sync();
  gemm_stream(p.X1b, p.W2b, 1024, p.b2, p.Xlb, nullptr, 0, lds, w, l, wm, wn,
              lhi, llo, m0, n0);
  grid.sync();
  gemm_stream(p.Xlb, p.Wihb, 1024, nullptr, nullptr, p.xw, 2, lds, w, l, wm,
              wn, lhi, llo, m0, n0);
  grid.sync();

  // ---- load resident Wsum slab: rows n0..n0+63, K=1024 (128 KB) ----
  short* slab = (short*)lds;
  {
    const ushort_t* Wn = p.Wsmb + ((size_t)n0 << 10);
#pragma unroll
    for (int i = 0; i < 32; ++i) {
      int c = t + (i << 8);  // 0..8191 chunks of 8 elems
      int r = c >> 7, cc = c & 127;
      int pc = (cc & ~7) | ((cc & 7) ^ (r & 7));
      short8 v = *(const short8*)(Wn + ((size_t)r << 10) + (cc << 3));
      *(short8*)(slab + (r << 10) + (pc << 3)) = v;
    }
  }
  __syncthreads();

  short* Ab[2] = {(short*)(lds + 131072), (short*)(lds + 139264)};
  short* Bsg = (short*)(lds + 147456);
  ushort_t* Hb[2] = {p.Hb0, p.Hb1};

  // ---- 64 RNN steps ----
  for (int st = 0; st < 64; ++st) {
    const ushort_t* Asrc = (st == 0) ? p.Xlb : Hb[st & 1];
    const ushort_t* Arow = Asrc + ((size_t)m0 << 10);
    bool flag = st && !(st & 15);  // t=16,32,48: h@Whh^T + xw
    floatx4 acc[2][2];
#pragma unroll
    for (int i = 0; i < 2; ++i)
#pragma unroll
      for (int j = 0; j < 2; ++j) acc[i][j] = (floatx4){0.f, 0.f, 0.f, 0.f};

    if (!flag) {
      // resident-B path: A double-buffered, raw barriers, vmcnt pipelining
      stage64(Arow, 1024, Ab[0], w, l);
      for (int c = 0; c < 16; ++c) {
        if (c < 15) {
          stage64(Arow + ((c + 1) << 6), 1024, Ab[(c + 1) & 1], w, l);
          WAIT_VM2();
        } else {
          WAIT_VM0();
        }
        BAR();
        compute_chunk(Ab[c & 1], slab, 1024, c << 6, acc, wm, wn, lhi, llo);
        BAR();
      }
    } else {
      const ushort_t* Brow = p.Whhb + ((size_t)n0 << 10);
      for (int c = 0; c < 16; ++c) {
        stage64(Arow + (c << 6), 1024, Ab[0], w, l);
        stage64(Brow + (c << 6), 1024, Bsg, w, l);
        WAIT_VM0();
        BAR();
        compute_chunk(Ab[0], Bsg, 64, 0, acc, wm, wn, lhi, llo);
        BAR();
      }
    }
    bool last = (st == 63);
    epilogue(acc, p.bias, flag ? p.xw : nullptr,
             last ? nullptr : Hb[(st + 1) & 1], last ? p.hxout : nullptr, p.Wa,
             p.pacc, st, 1, m0, n0, wm, wn, lhi, llo);
    grid.sync();
  }

  // ---- finalize probs ----
  p.probs[gid] = fast_sigmoid(p.pacc[gid] + p.ba[0]);
}

extern "C" void kernel_launch(void* const* d_in, const int* in_sizes, int n_in,
                              void* d_out, int out_size, void* d_ws,
                              size_t ws_size, hipStream_t stream) {
  char* ws = (char*)d_ws;
  KP p;
  p.x = (const float*)d_in[0];
  p.W1 = (const float*)d_in[1];
  p.b1 = (const float*)d_in[2];
  p.W2 = (const float*)d_in[3];
  p.b2 = (const float*)d_in[4];
  p.Wih = (const float*)d_in[5];
  p.Whh = (const float*)d_in[6];
  p.bih = (const float*)d_in[7];
  p.bhh = (const float*)d_in[8];
  p.Wa = (const float*)d_in[9];
  p.ba = (const float*)d_in[10];
  p.Xb = (ushort_t*)(ws);
  p.W1b = (ushort_t*)(ws + ((size_t)8 << 20));
  p.W2b = (ushort_t*)(ws + ((size_t)16 << 20));
  p.Wihb = (ushort_t*)(ws + ((size_t)18 << 20));
  p.Whhb = (ushort_t*)(ws + ((size_t)20 << 20));
  p.Wsmb = (ushort_t*)(ws + ((size_t)22 << 20));
  p.X1b = (ushort_t*)(ws + ((size_t)24 << 20));
  p.Xlb = (ushort_t*)(ws + ((size_t)26 << 20));
  p.Hb0 = (ushort_t*)(ws + ((size_t)28 << 20));
  p.Hb1 = (ushort_t*)(ws + ((size_t)30 << 20));
  p.xw = (float*)(ws + ((size_t)32 << 20));
  p.bias = (float*)(ws + ((size_t)36 << 20));
  p.pacc = (float*)(ws + ((size_t)36 << 20) + 4096);
  p.probs = (float*)d_out;
  p.hxout = (float*)d_out + 65536;

  hipFuncSetAttribute((const void*)fused_rnn,
                      hipFuncAttributeMaxDynamicSharedMemorySize, 155648);
  void* args[] = {&p};
  hipLaunchCooperativeKernel((const void*)fused_rnn, dim3(256), dim3(256),
                             args, 155648, stream);
}

// Round 3
// 1895.172 us; speedup vs baseline: 1.4255x; 1.4255x over previous
//
#include <hip/hip_runtime.h>
#include <hip/hip_cooperative_groups.h>

namespace cg = cooperative_groups;

typedef unsigned short ushort_t;
typedef __attribute__((ext_vector_type(8))) short short8;
typedef __attribute__((ext_vector_type(4))) float floatx4;
typedef __attribute__((ext_vector_type(4))) ushort_t us4;

#define BAR() __builtin_amdgcn_s_barrier()

__device__ __forceinline__ ushort_t f2bf(float f) {
  union { float f; unsigned u; } v; v.f = f;
  unsigned r = v.u + 0x7fffu + ((v.u >> 16) & 1u);
  return (ushort_t)(r >> 16);
}
__device__ __forceinline__ float fast_sigmoid(float x) {
  return 1.f / (1.f + __expf(-x));
}
__device__ __forceinline__ float fast_tanh(float x) {
  return 1.f - 2.f / (__expf(2.f * x) + 1.f);
}

__device__ __forceinline__ void gld16(const void* g, void* l) {
  __builtin_amdgcn_global_load_lds(
      (__attribute__((address_space(1))) void*)g,
      (__attribute__((address_space(3))) void*)l, 16, 0, 0);
}

// Stage a 64x64 bf16 chunk (rows x k) into an 8KB LDS chunk, XOR-swizzled.
__device__ __forceinline__ void stage64(const ushort_t* src, int ldk,
                                        short* dst, int w, int l) {
  int r0 = (w << 3) + (l >> 3);
  int cb0 = (l & 7) ^ (r0 & 7);
  int r1 = 32 + r0;
  int cb1 = (l & 7) ^ (r1 & 7);
  gld16(src + (size_t)r0 * ldk + (cb0 << 3), dst + (w << 9));
  gld16(src + (size_t)r1 * ldk + (cb1 << 3), dst + 2048 + (w << 9));
}

__device__ __forceinline__ void compute_chunk64(const short* As, const short* Bs,
                                                floatx4 acc[2][2], int wm,
                                                int wn, int lhi, int llo) {
#pragma unroll
  for (int ks = 0; ks < 2; ++ks) {
    short8 a[2], b[2];
#pragma unroll
    for (int tm = 0; tm < 2; ++tm) {
      int m = (wm << 5) + (tm << 4) + llo;
      int ph = ((ks << 2) + lhi) ^ (m & 7);
      a[tm] = *(const short8*)(As + m * 64 + (ph << 3));
    }
#pragma unroll
    for (int tn = 0; tn < 2; ++tn) {
      int n = (wn << 5) + (tn << 4) + llo;
      int ph = ((ks << 2) + lhi) ^ (n & 7);
      b[tn] = *(const short8*)(Bs + n * 64 + (ph << 3));
    }
#pragma unroll
    for (int tm = 0; tm < 2; ++tm)
#pragma unroll
      for (int tn = 0; tn < 2; ++tn)
        acc[tm][tn] = __builtin_amdgcn_mfma_f32_16x16x32_bf16(
            a[tm], b[tn], acc[tm][tn], 0, 0, 0);
  }
}

__device__ __forceinline__ void ff_epilogue(floatx4 acc[2][2], const float* bias,
                                            ushort_t* outb, float* outf, int act,
                                            int m0, int n0, int wm, int wn,
                                            int lhi, int llo) {
#pragma unroll
  for (int tm = 0; tm < 2; ++tm)
#pragma unroll
    for (int tn = 0; tn < 2; ++tn)
#pragma unroll
      for (int i = 0; i < 4; ++i) {
        int gm = m0 + (wm << 5) + (tm << 4) + (lhi << 2) + i;
        int gn = n0 + (wn << 5) + (tn << 4) + llo;
        float v = acc[tm][tn][i];
        if (bias) v += bias[gn];
        if (act == 0) v = fmaxf(v, 0.f);
        if (outb) outb[((size_t)gm << 10) + gn] = f2bf(v);
        if (outf) outf[((size_t)gm << 10) + gn] = v;
      }
}

// Depth-4 ring staged GEMM for the feed-forward phases.
__device__ void gemm_stream4(const ushort_t* A, const ushort_t* W, int K,
                             const float* bias, ushort_t* outb, float* outf,
                             int act, char* lds, int w, int l, int wm, int wn,
                             int lhi, int llo, int m0, int n0) {
  short* Ab[4] = {(short*)lds, (short*)(lds + 8192), (short*)(lds + 16384),
                  (short*)(lds + 24576)};
  short* Bb[4] = {(short*)(lds + 32768), (short*)(lds + 40960),
                  (short*)(lds + 49152), (short*)(lds + 57344)};
  floatx4 acc[2][2];
#pragma unroll
  for (int i = 0; i < 2; ++i)
#pragma unroll
    for (int j = 0; j < 2; ++j) acc[i][j] = (floatx4){0.f, 0.f, 0.f, 0.f};
  const ushort_t* Abase = A + (size_t)m0 * K;
  const ushort_t* Bbase = W + (size_t)n0 * K;
  int nc = K >> 6;
#pragma unroll
  for (int c0 = 0; c0 < 3; ++c0) {
    stage64(Abase + (c0 << 6), K, Ab[c0], w, l);
    stage64(Bbase + (c0 << 6), K, Bb[c0], w, l);
  }
  for (int c = 0; c < nc; ++c) {
    int nxt = c + 3;
    if (nxt < nc) {
      stage64(Abase + (nxt << 6), K, Ab[nxt & 3], w, l);
      stage64(Bbase + (nxt << 6), K, Bb[nxt & 3], w, l);
      __builtin_amdgcn_s_waitcnt(0x0F70 | 12);
    } else if (nc - c == 3) {
      __builtin_amdgcn_s_waitcnt(0x0F70 | 8);
    } else if (nc - c == 2) {
      __builtin_amdgcn_s_waitcnt(0x0F70 | 4);
    } else {
      __builtin_amdgcn_s_waitcnt(0x0F70);
    }
    BAR();
    compute_chunk64(Ab[c & 3], Bb[c & 3], acc, wm, wn, lhi, llo);
    BAR();
  }
  ff_epilogue(acc, bias, outb, outf, act, m0, n0, wm, wn, lhi, llo);
}

// Two-level grid barrier: 16 group counters (64B apart) + root. Monotone targets.
__device__ __forceinline__ void gbar(unsigned* area, unsigned seq, int t, int bid) {
  __syncthreads();
  if (t == 0) {
    __threadfence();  // release: make this block's stores agent-visible
    unsigned old = atomicAdd(&area[(bid & 15) << 4], 1u);
    if (old == (seq << 4) - 1u) atomicAdd(&area[256], 1u);
    while (__hip_atomic_load(&area[256], __ATOMIC_RELAXED,
                             __HIP_MEMORY_SCOPE_AGENT) < (seq << 4))
      __builtin_amdgcn_s_sleep(1);
    __threadfence();  // acquire: invalidate stale cached h
  }
  __syncthreads();
}

// RNN step compute: A (and B when FLAG) fragments register-prefetched in
// groups of 4 chunks; B from resident LDS slab when !FLAG. No barriers.
template <bool FLAG>
__device__ __forceinline__ void rnn_step(const ushort_t* __restrict__ Ab,
                                         const ushort_t* __restrict__ Bb,
                                         const short* __restrict__ slab,
                                         floatx4 acc[2][2], int wn, int lhi,
                                         int llo) {
  short8 af[2][4][2][2];
  short8 bfr[2][4][2][2];
#pragma unroll
  for (int cc = 0; cc < 4; ++cc)
#pragma unroll
    for (int ks = 0; ks < 2; ++ks)
#pragma unroll
      for (int tm = 0; tm < 2; ++tm) {
        af[0][cc][ks][tm] =
            *(const short8*)(Ab + tm * 16384 + (cc << 6) + ks * 32);
        if (FLAG)
          bfr[0][cc][ks][tm] =
              *(const short8*)(Bb + tm * 16384 + (cc << 6) + ks * 32);
      }
#pragma unroll
  for (int g = 0; g < 4; ++g) {
    if (g < 3) {
      int gb = (g + 1) & 1;
#pragma unroll
      for (int cc = 0; cc < 4; ++cc)
#pragma unroll
        for (int ks = 0; ks < 2; ++ks)
#pragma unroll
          for (int tm = 0; tm < 2; ++tm) {
            af[gb][cc][ks][tm] = *(const short8*)(Ab + tm * 16384 +
                                                  (((g + 1) * 4 + cc) << 6) +
                                                  ks * 32);
            if (FLAG)
              bfr[gb][cc][ks][tm] = *(const short8*)(Bb + tm * 16384 +
                                                     (((g + 1) * 4 + cc) << 6) +
                                                     ks * 32);
          }
    }
#pragma unroll
    for (int cc = 0; cc < 4; ++cc) {
      int c = g * 4 + cc;
#pragma unroll
      for (int ks = 0; ks < 2; ++ks) {
        short8 b0, b1;
        if (FLAG) {
          b0 = bfr[g & 1][cc][ks][0];
          b1 = bfr[g & 1][cc][ks][1];
        } else {
          int n_0 = (wn << 5) + llo;
          int ph0 = ((ks << 2) + lhi) ^ (n_0 & 7);
          b0 = *(const short8*)(slab + n_0 * 1024 + (c << 6) + (ph0 << 3));
          int n_1 = n_0 + 16;
          int ph1 = ((ks << 2) + lhi) ^ (n_1 & 7);
          b1 = *(const short8*)(slab + n_1 * 1024 + (c << 6) + (ph1 << 3));
        }
#pragma unroll
        for (int tm = 0; tm < 2; ++tm) {
          acc[tm][0] = __builtin_amdgcn_mfma_f32_16x16x32_bf16(
              af[g & 1][cc][ks][tm], b0, acc[tm][0], 0, 0, 0);
          acc[tm][1] = __builtin_amdgcn_mfma_f32_16x16x32_bf16(
              af[g & 1][cc][ks][tm], b1, acc[tm][1], 0, 0, 0);
        }
      }
    }
  }
}

struct KP {
  const float *x, *W1, *b1, *W2, *b2, *Wih, *Whh, *bih, *bhh, *Wa, *ba;
  ushort_t *Xb, *W1b, *W2b, *Wihb, *Whhb, *Wsmb, *X1b, *Xlb, *Hb0, *Hb1;
  float *xw, *bias, *pacc, *probs, *hxout;
  unsigned* barrier;
};

__global__ __launch_bounds__(256, 1) void fused_rnn(KP p) {
  extern __shared__ char lds[];
  cg::grid_group grid = cg::this_grid();
  const int t = threadIdx.x;
  const int w = t >> 6, l = t & 63;
  const int wm = w >> 1, wn = w & 1;
  const int lhi = l >> 4, llo = l & 15;
  const int bid = blockIdx.x;
  const int m0 = (bid >> 4) << 6, n0 = (bid & 15) << 6;
  const int gid = bid * 256 + t;

  // ---- phase 0: casts, Wsum, bias, pacc + barrier zero ----
  {
    const float4* xf = (const float4*)p.x;
    const float4* w1f = (const float4*)p.W1;
    const float4* w2f = (const float4*)p.W2;
    const float4* wif = (const float4*)p.Wih;
    const float4* whf = (const float4*)p.Whh;
    for (int i = gid; i < 1048576; i += 65536) {
      float4 v = xf[i];
      us4 o;
      o.x = f2bf(v.x); o.y = f2bf(v.y); o.z = f2bf(v.z); o.w = f2bf(v.w);
      ((us4*)p.Xb)[i] = o;
      float4 u = w1f[i];
      o.x = f2bf(u.x); o.y = f2bf(u.y); o.z = f2bf(u.z); o.w = f2bf(u.w);
      ((us4*)p.W1b)[i] = o;
      if (i < 262144) {
        float4 a = w2f[i];
        o.x = f2bf(a.x); o.y = f2bf(a.y); o.z = f2bf(a.z); o.w = f2bf(a.w);
        ((us4*)p.W2b)[i] = o;
        float4 pp = wif[i];
        o.x = f2bf(pp.x); o.y = f2bf(pp.y); o.z = f2bf(pp.z); o.w = f2bf(pp.w);
        ((us4*)p.Wihb)[i] = o;
        float4 q = whf[i];
        o.x = f2bf(q.x); o.y = f2bf(q.y); o.z = f2bf(q.z); o.w = f2bf(q.w);
        ((us4*)p.Whhb)[i] = o;
        o.x = f2bf(pp.x + q.x); o.y = f2bf(pp.y + q.y);
        o.z = f2bf(pp.z + q.z); o.w = f2bf(pp.w + q.w);
        ((us4*)p.Wsmb)[i] = o;
      }
    }
    p.pacc[gid] = 0.f;
    if (gid < 1024) p.bias[gid] = p.bih[gid] + p.bhh[gid];
    if (gid < 512) p.barrier[gid] = 0u;
  }
  grid.sync();

  // ---- FF phases ----
  gemm_stream4(p.Xb, p.W1b, 4096, p.b1, p.X1b, nullptr, 0, lds, w, l, wm, wn,
               lhi, llo, m0, n0);
  gbar(p.barrier, 1, t, bid);
  gemm_stream4(p.X1b, p.W2b, 1024, p.b2, p.Xlb, nullptr, 0, lds, w, l, wm, wn,
               lhi, llo, m0, n0);
  gbar(p.barrier, 2, t, bid);
  gemm_stream4(p.Xlb, p.Wihb, 1024, nullptr, nullptr, p.xw, 2, lds, w, l, wm,
               wn, lhi, llo, m0, n0);
  gbar(p.barrier, 3, t, bid);

  // ---- resident Wsum slab: rows n0..n0+63, K=1024 (128 KB) ----
  short* slab = (short*)lds;
  {
    const ushort_t* Wn = p.Wsmb + ((size_t)n0 << 10);
#pragma unroll
    for (int i = 0; i < 32; ++i) {
      int c = t + (i << 8);
      int r = c >> 7, cc = c & 127;
      int pc = (cc & ~7) | ((cc & 7) ^ (r & 7));
      short8 v = *(const short8*)(Wn + ((size_t)r << 10) + (cc << 3));
      *(short8*)(slab + (r << 10) + (pc << 3)) = v;
    }
  }
  __syncthreads();

  ushort_t* Hb[2] = {p.Hb0, p.Hb1};
  const int aoff = ((wm << 5) + llo) << 10;  // per-lane A base offset (elems)
  const int boff = ((wn << 5) + llo) << 10;

  for (int st = 0; st < 64; ++st) {
    const ushort_t* Asrc = (st == 0) ? p.Xlb : Hb[st & 1];
    const ushort_t* Ab = Asrc + ((size_t)m0 << 10) + aoff + (lhi << 3);
    const ushort_t* Bb = p.Whhb + ((size_t)n0 << 10) + boff + (lhi << 3);
    bool flag = st && !(st & 15);
    floatx4 acc[2][2];
#pragma unroll
    for (int i = 0; i < 2; ++i)
#pragma unroll
      for (int j = 0; j < 2; ++j) acc[i][j] = (floatx4){0.f, 0.f, 0.f, 0.f};

    if (flag)
      rnn_step<true>(Ab, Bb, slab, acc, wn, lhi, llo);
    else
      rnn_step<false>(Ab, Bb, slab, acc, wn, lhi, llo);

    // epilogue
    bool last = (st == 63);
    ushort_t* Hn = Hb[(st + 1) & 1];
    float hv[2][2][4];
#pragma unroll
    for (int tm = 0; tm < 2; ++tm)
#pragma unroll
      for (int tn = 0; tn < 2; ++tn)
#pragma unroll
        for (int i = 0; i < 4; ++i) {
          int gm = m0 + (wm << 5) + (tm << 4) + (lhi << 2) + i;
          int gn = n0 + (wn << 5) + (tn << 4) + llo;
          float v = acc[tm][tn][i];
          v += p.bias[gn];
          if (flag) v += p.xw[((size_t)gm << 10) + gn];
          v = fast_tanh(v);
          if (last) p.hxout[((size_t)gm << 10) + gn] = v;
          else Hn[((size_t)gm << 10) + gn] = f2bf(v);
          hv[tm][tn][i] = v;
        }
#pragma unroll
    for (int tm = 0; tm < 2; ++tm)
#pragma unroll
      for (int i = 0; i < 4; ++i) {
        float s = 0.f;
#pragma unroll
        for (int tn = 0; tn < 2; ++tn)
          s += hv[tm][tn][i] * p.Wa[n0 + (wn << 5) + (tn << 4) + llo];
        s += __shfl_xor(s, 1);
        s += __shfl_xor(s, 2);
        s += __shfl_xor(s, 4);
        s += __shfl_xor(s, 8);
        if (llo == 0)
          atomicAdd(&p.pacc[st * 1024 + m0 + (wm << 5) + (tm << 4) + (lhi << 2) + i], s);
      }
    gbar(p.barrier, 4 + st, t, bid);
  }

  p.probs[gid] = fast_sigmoid(p.pacc[gid] + p.ba[0]);
}

extern "C" void kernel_launch(void* const* d_in, const int* in_sizes, int n_in,
                              void* d_out, int out_size, void* d_ws,
                              size_t ws_size, hipStream_t stream) {
  char* ws = (char*)d_ws;
  KP p;
  p.x = (const float*)d_in[0];
  p.W1 = (const float*)d_in[1];
  p.b1 = (const float*)d_in[2];
  p.W2 = (const float*)d_in[3];
  p.b2 = (const float*)d_in[4];
  p.Wih = (const float*)d_in[5];
  p.Whh = (const float*)d_in[6];
  p.bih = (const float*)d_in[7];
  p.bhh = (const float*)d_in[8];
  p.Wa = (const float*)d_in[9];
  p.ba = (const float*)d_in[10];
  p.Xb = (ushort_t*)(ws);
  p.W1b = (ushort_t*)(ws + ((size_t)8 << 20));
  p.W2b = (ushort_t*)(ws + ((size_t)16 << 20));
  p.Wihb = (ushort_t*)(ws + ((size_t)18 << 20));
  p.Whhb = (ushort_t*)(ws + ((size_t)20 << 20));
  p.Wsmb = (ushort_t*)(ws + ((size_t)22 << 20));
  p.X1b = (ushort_t*)(ws + ((size_t)24 << 20));
  p.Xlb = (ushort_t*)(ws + ((size_t)26 << 20));
  p.Hb0 = (ushort_t*)(ws + ((size_t)28 << 20));
  p.Hb1 = (ushort_t*)(ws + ((size_t)30 << 20));
  p.xw = (float*)(ws + ((size_t)32 << 20));
  p.bias = (float*)(ws + ((size_t)36 << 20));
  p.pacc = (float*)(ws + ((size_t)36 << 20) + 4096);
  p.barrier = (unsigned*)(ws + ((size_t)36 << 20) + 4096 + 262144);
  p.probs = (float*)d_out;
  p.hxout = (float*)d_out + 65536;

  hipFuncSetAttribute((const void*)fused_rnn,
                      hipFuncAttributeMaxDynamicSharedMemorySize, 131072);
  void* args[] = {&p};
  hipLaunchCooperativeKernel((const void*)fused_rnn, dim3(256), dim3(256),
                             args, 131072, stream);
}

// Round 4
// 766.466 us; speedup vs baseline: 3.5248x; 2.4726x over previous
//
#include <hip/hip_runtime.h>
#include <hip/hip_cooperative_groups.h>

namespace cg = cooperative_groups;

typedef unsigned short ushort_t;
typedef __attribute__((ext_vector_type(8))) short short8;
typedef __attribute__((ext_vector_type(4))) float floatx4;
typedef __attribute__((ext_vector_type(4))) ushort_t us4;

#define BAR() __builtin_amdgcn_s_barrier()
#define WAITVM(n) __builtin_amdgcn_s_waitcnt(0x0F70 | (n))
#define CBARRIER() __asm__ __volatile__("" ::: "memory")

__device__ __forceinline__ ushort_t f2bf(float f) {
  union { float f; unsigned u; } v; v.f = f;
  unsigned r = v.u + 0x7fffu + ((v.u >> 16) & 1u);
  return (ushort_t)(r >> 16);
}
__device__ __forceinline__ float fast_sigmoid(float x) {
  return 1.f / (1.f + __expf(-x));
}
__device__ __forceinline__ float fast_tanh(float x) {
  return 1.f - 2.f / (__expf(2.f * x) + 1.f);
}

template <int AUX>
__device__ __forceinline__ void gld16x(const void* g, void* l) {
  __builtin_amdgcn_global_load_lds(
      (__attribute__((address_space(1))) void*)g,
      (__attribute__((address_space(3))) void*)l, 16, 0, AUX);
}

// ---- FF staging (round-1/3 proven): 64x64 chunk, 8KB, XOR-8 swizzle ----
__device__ __forceinline__ void stage64(const ushort_t* src, int ldk,
                                        short* dst, int w, int l) {
  int r0 = (w << 3) + (l >> 3);
  int cb0 = (l & 7) ^ (r0 & 7);
  int r1 = 32 + r0;
  int cb1 = (l & 7) ^ (r1 & 7);
  gld16x<0>(src + (size_t)r0 * ldk + (cb0 << 3), dst + (w << 9));
  gld16x<0>(src + (size_t)r1 * ldk + (cb1 << 3), dst + 2048 + (w << 9));
}

__device__ __forceinline__ void compute_chunk64(const short* As, const short* Bs,
                                                floatx4 acc[2][2], int wm,
                                                int wn, int lhi, int llo) {
#pragma unroll
  for (int ks = 0; ks < 2; ++ks) {
    short8 a[2], b[2];
#pragma unroll
    for (int tm = 0; tm < 2; ++tm) {
      int m = (wm << 5) + (tm << 4) + llo;
      int ph = ((ks << 2) + lhi) ^ (m & 7);
      a[tm] = *(const short8*)(As + m * 64 + (ph << 3));
    }
#pragma unroll
    for (int tn = 0; tn < 2; ++tn) {
      int n = (wn << 5) + (tn << 4) + llo;
      int ph = ((ks << 2) + lhi) ^ (n & 7);
      b[tn] = *(const short8*)(Bs + n * 64 + (ph << 3));
    }
#pragma unroll
    for (int tm = 0; tm < 2; ++tm)
#pragma unroll
      for (int tn = 0; tn < 2; ++tn)
        acc[tm][tn] = __builtin_amdgcn_mfma_f32_16x16x32_bf16(
            a[tm], b[tn], acc[tm][tn], 0, 0, 0);
  }
}

__device__ __forceinline__ void ff_epilogue(floatx4 acc[2][2], const float* bias,
                                            ushort_t* outb, float* outf, int act,
                                            int m0, int n0, int wm, int wn,
                                            int lhi, int llo) {
#pragma unroll
  for (int tm = 0; tm < 2; ++tm)
#pragma unroll
    for (int tn = 0; tn < 2; ++tn)
#pragma unroll
      for (int i = 0; i < 4; ++i) {
        int gm = m0 + (wm << 5) + (tm << 4) + (lhi << 2) + i;
        int gn = n0 + (wn << 5) + (tn << 4) + llo;
        float v = acc[tm][tn][i];
        if (bias) v += bias[gn];
        if (act == 0) v = fmaxf(v, 0.f);
        if (outb) outb[((size_t)gm << 10) + gn] = f2bf(v);
        if (outf) outf[((size_t)gm << 10) + gn] = v;
      }
}

__device__ void gemm_stream4(const ushort_t* A, const ushort_t* W, int K,
                             const float* bias, ushort_t* outb, float* outf,
                             int act, char* lds, int w, int l, int wm, int wn,
                             int lhi, int llo, int m0, int n0) {
  short* Ab[4] = {(short*)lds, (short*)(lds + 8192), (short*)(lds + 16384),
                  (short*)(lds + 24576)};
  short* Bb[4] = {(short*)(lds + 32768), (short*)(lds + 40960),
                  (short*)(lds + 49152), (short*)(lds + 57344)};
  floatx4 acc[2][2];
#pragma unroll
  for (int i = 0; i < 2; ++i)
#pragma unroll
    for (int j = 0; j < 2; ++j) acc[i][j] = (floatx4){0.f, 0.f, 0.f, 0.f};
  const ushort_t* Abase = A + (size_t)m0 * K;
  const ushort_t* Bbase = W + (size_t)n0 * K;
  int nc = K >> 6;
#pragma unroll
  for (int c0 = 0; c0 < 3; ++c0) {
    stage64(Abase + (c0 << 6), K, Ab[c0], w, l);
    stage64(Bbase + (c0 << 6), K, Bb[c0], w, l);
  }
  for (int c = 0; c < nc; ++c) {
    int nxt = c + 3;
    if (nxt < nc) {
      stage64(Abase + (nxt << 6), K, Ab[nxt & 3], w, l);
      stage64(Bbase + (nxt << 6), K, Bb[nxt & 3], w, l);
      WAITVM(12);
    } else if (nc - c == 3) {
      WAITVM(8);
    } else if (nc - c == 2) {
      WAITVM(4);
    } else {
      WAITVM(0);
    }
    BAR();
    CBARRIER();
    compute_chunk64(Ab[c & 3], Bb[c & 3], acc, wm, wn, lhi, llo);
    BAR();
  }
  ff_epilogue(acc, bias, outb, outf, act, m0, n0, wm, wn, lhi, llo);
}

// Two-level global barrier with full fences (FF phases only).
__device__ __forceinline__ void gbar(unsigned* area, unsigned seq, int t, int bid) {
  __syncthreads();
  if (t == 0) {
    __threadfence();
    unsigned old = atomicAdd(&area[(bid & 15) << 4], 1u);
    if (old == (seq << 4) - 1u) atomicAdd(&area[256], 1u);
    while (__hip_atomic_load(&area[256], __ATOMIC_RELAXED,
                             __HIP_MEMORY_SCOPE_AGENT) < (seq << 4))
      __builtin_amdgcn_s_sleep(1);
    __threadfence();
  }
  __syncthreads();
}

// RNN chunk staging: 64 rows x 32 k (4KB). Phys 16B-unit p = r*4 + (s^((r>>1)&3)).
// One gld16 per wave. AUX=17 (sc0|sc1) for h (device-coherent), 0 for weights.
template <int AUX>
__device__ __forceinline__ void stage_chunk(const ushort_t* src, short* slot,
                                            int w, int l) {
  int pu = (w << 6) + l;              // phys unit 0..255
  int r = pu >> 2;                    // row
  int sg = (pu & 3) ^ ((r >> 1) & 3); // global 16B segment
  gld16x<AUX>(src + ((size_t)r << 10) + (sg << 3), slot + (w << 9));
}

struct KP {
  const float *x, *W1, *b1, *W2, *b2, *Wih, *Whh, *bih, *bhh, *Wa, *ba;
  ushort_t *Xb, *W1b, *W2b, *Wihb, *Whhb, *Wsmb, *X1b, *Xlb, *Hb0, *Hb1;
  float *xw, *bias, *pacc, *probs, *hxout;
  unsigned* barrier;
};

__global__ __launch_bounds__(256, 1) void fused_rnn(KP p) {
  extern __shared__ char lds[];
  cg::grid_group grid = cg::this_grid();
  const int t = threadIdx.x;
  const int w = t >> 6, l = t & 63;
  const int wm = w >> 1, wn = w & 1;
  const int lhi = l >> 4, llo = l & 15;
  const int bid = blockIdx.x;
  const int m0 = (bid >> 4) << 6, n0 = (bid & 15) << 6;
  const int mgrp = bid >> 4;
  const int gid = bid * 256 + t;

  // ---- phase 0: casts, Wsum, bias, zero pacc + barriers ----
  {
    const float4* xf = (const float4*)p.x;
    const float4* w1f = (const float4*)p.W1;
    const float4* w2f = (const float4*)p.W2;
    const float4* wif = (const float4*)p.Wih;
    const float4* whf = (const float4*)p.Whh;
    for (int i = gid; i < 1048576; i += 65536) {
      float4 v = xf[i];
      us4 o;
      o.x = f2bf(v.x); o.y = f2bf(v.y); o.z = f2bf(v.z); o.w = f2bf(v.w);
      ((us4*)p.Xb)[i] = o;
      float4 u = w1f[i];
      o.x = f2bf(u.x); o.y = f2bf(u.y); o.z = f2bf(u.z); o.w = f2bf(u.w);
      ((us4*)p.W1b)[i] = o;
      if (i < 262144) {
        float4 a = w2f[i];
        o.x = f2bf(a.x); o.y = f2bf(a.y); o.z = f2bf(a.z); o.w = f2bf(a.w);
        ((us4*)p.W2b)[i] = o;
        float4 pp = wif[i];
        o.x = f2bf(pp.x); o.y = f2bf(pp.y); o.z = f2bf(pp.z); o.w = f2bf(pp.w);
        ((us4*)p.Wihb)[i] = o;
        float4 q = whf[i];
        o.x = f2bf(q.x); o.y = f2bf(q.y); o.z = f2bf(q.z); o.w = f2bf(q.w);
        ((us4*)p.Whhb)[i] = o;
        o.x = f2bf(pp.x + q.x); o.y = f2bf(pp.y + q.y);
        o.z = f2bf(pp.z + q.z); o.w = f2bf(pp.w + q.w);
        ((us4*)p.Wsmb)[i] = o;
      }
    }
    p.pacc[gid] = 0.f;
    if (gid < 1024) p.bias[gid] = p.bih[gid] + p.bhh[gid];
    if (gid < 1024) p.barrier[gid] = 0u;
  }
  grid.sync();  // also publishes the zeroed barrier area

  // ---- FF phases ----
  gemm_stream4(p.Xb, p.W1b, 4096, p.b1, p.X1b, nullptr, 0, lds, w, l, wm, wn,
               lhi, llo, m0, n0);
  gbar(p.barrier, 1, t, bid);
  gemm_stream4(p.X1b, p.W2b, 1024, p.b2, p.Xlb, nullptr, 0, lds, w, l, wm, wn,
               lhi, llo, m0, n0);
  gbar(p.barrier, 2, t, bid);
  gemm_stream4(p.Xlb, p.Wihb, 1024, nullptr, nullptr, p.xw, 2, lds, w, l, wm,
               wn, lhi, llo, m0, n0);
  gbar(p.barrier, 3, t, bid);

  // ---- resident Wsum slab (A-operand rows = n0..n0+63), 128 KB ----
  short* slab = (short*)lds;
  {
    const ushort_t* Wn = p.Wsmb + ((size_t)n0 << 10);
#pragma unroll
    for (int i = 0; i < 32; ++i) {
      int c = t + (i << 8);
      int r = c >> 7, cc = c & 127;
      int pc = (cc & ~7) | ((cc & 7) ^ (r & 7));
      short8 v = *(const short8*)(Wn + ((size_t)r << 10) + (cc << 3));
      *(short8*)(slab + (r << 10) + (pc << 3)) = v;
    }
  }
  __syncthreads();

  short* ring = (short*)(lds + 131072);  // 6 slots x 4KB (2048 shorts each)
  ushort_t* Hb[2] = {p.Hb0, p.Hb1};
  unsigned* mbar = p.barrier + 320 + (mgrp << 4);

  // ---- register preloads (loop-invariant; no fences in loop keep them live) ----
  int gnb[2], gmv[2];
#pragma unroll
  for (int tn = 0; tn < 2; ++tn) gnb[tn] = n0 + (wn << 5) + (tn << 4) + (lhi << 2);
#pragma unroll
  for (int tm = 0; tm < 2; ++tm) gmv[tm] = m0 + (wm << 5) + (tm << 4) + llo;
  float bias_r[2][4], wa_r[2][4], xw_r[2][2][4];
#pragma unroll
  for (int tn = 0; tn < 2; ++tn)
#pragma unroll
    for (int i = 0; i < 4; ++i) {
      bias_r[tn][i] = p.bias[gnb[tn] + i];
      wa_r[tn][i] = p.Wa[gnb[tn] + i];
    }
#pragma unroll
  for (int tm = 0; tm < 2; ++tm)
#pragma unroll
    for (int tn = 0; tn < 2; ++tn)
#pragma unroll
      for (int i = 0; i < 4; ++i)
        xw_r[tm][tn][i] = p.xw[((size_t)gmv[tm] << 10) + gnb[tn] + i];

  // ---- 64 RNN steps, fence-free; h via device-coherent (sc0 sc1) path ----
  for (int st = 0; st < 64; ++st) {
    const ushort_t* hbase =
        ((st == 0) ? p.Xlb : Hb[st & 1]) + ((size_t)m0 << 10);
    bool flag = st && !(st & 15);
    floatx4 acc[2][2];  // [tn][tm]
#pragma unroll
    for (int i = 0; i < 2; ++i)
#pragma unroll
      for (int j = 0; j < 2; ++j) acc[i][j] = (floatx4){0.f, 0.f, 0.f, 0.f};

    if (!flag) {
      // B = h from ring (6 deep), A = Wsum slab (resident)
#pragma unroll
      for (int j = 0; j < 4; ++j)
        stage_chunk<17>(hbase + (j << 5), ring + j * 2048, w, l);
#pragma unroll
      for (int c = 0; c < 32; ++c) {
        if (c <= 28) WAITVM(3);
        else if (c == 29) WAITVM(2);
        else if (c == 30) WAITVM(1);
        else WAITVM(0);
        BAR();
        CBARRIER();
        if (c + 4 < 32)
          stage_chunk<17>(hbase + ((c + 4) << 5), ring + ((c + 4) % 6) * 2048,
                          w, l);
        const short* hslot = ring + (c % 6) * 2048;
        short8 afr[2], bfr[2];
#pragma unroll
        for (int tn = 0; tn < 2; ++tn) {
          int na = (wn << 5) + (tn << 4) + llo;
          int u = (c << 2) + lhi;
          int pu = (u & ~7) | ((u & 7) ^ (na & 7));
          afr[tn] = *(const short8*)(slab + (na << 10) + (pu << 3));
        }
#pragma unroll
        for (int tm = 0; tm < 2; ++tm) {
          int mb = (wm << 5) + (tm << 4) + llo;
          bfr[tm] =
              *(const short8*)(hslot + mb * 32 + ((lhi ^ ((mb >> 1) & 3)) << 3));
        }
#pragma unroll
        for (int tn = 0; tn < 2; ++tn)
#pragma unroll
          for (int tm = 0; tm < 2; ++tm)
            acc[tn][tm] = __builtin_amdgcn_mfma_f32_16x16x32_bf16(
                afr[tn], bfr[tm], acc[tn][tm], 0, 0, 0);
      }
    } else {
      // A = Whh rows (staged, cacheable), B = h (coherent); paired depth-3
      const ushort_t* wbase = p.Whhb + ((size_t)n0 << 10);
#pragma unroll
      for (int j = 0; j < 2; ++j) {
        stage_chunk<0>(wbase + (j << 5), ring + j * 2048, w, l);
        stage_chunk<17>(hbase + (j << 5), ring + (3 + j) * 2048, w, l);
      }
#pragma unroll
      for (int c = 0; c < 32; ++c) {
        if (c < 31) WAITVM(2);
        else WAITVM(0);
        BAR();
        CBARRIER();
        if (c + 2 < 32) {
          stage_chunk<0>(wbase + ((c + 2) << 5), ring + ((c + 2) % 3) * 2048,
                         w, l);
          stage_chunk<17>(hbase + ((c + 2) << 5),
                          ring + (3 + (c + 2) % 3) * 2048, w, l);
        }
        const short* wslot = ring + (c % 3) * 2048;
        const short* hslot = ring + (3 + c % 3) * 2048;
        short8 afr[2], bfr[2];
#pragma unroll
        for (int tn = 0; tn < 2; ++tn) {
          int na = (wn << 5) + (tn << 4) + llo;
          afr[tn] =
              *(const short8*)(wslot + na * 32 + ((lhi ^ ((na >> 1) & 3)) << 3));
        }
#pragma unroll
        for (int tm = 0; tm < 2; ++tm) {
          int mb = (wm << 5) + (tm << 4) + llo;
          bfr[tm] =
              *(const short8*)(hslot + mb * 32 + ((lhi ^ ((mb >> 1) & 3)) << 3));
        }
#pragma unroll
        for (int tn = 0; tn < 2; ++tn)
#pragma unroll
          for (int tm = 0; tm < 2; ++tm)
            acc[tn][tm] = __builtin_amdgcn_mfma_f32_16x16x32_bf16(
                afr[tn], bfr[tm], acc[tn][tm], 0, 0, 0);
      }
    }

    // ---- epilogue: D[r=n_local][c=m_local]; lane's 4 values k-contiguous in n
    bool last = (st == 63);
    ushort_t* Hnext = Hb[(st + 1) & 1];
    float hv[2][2][4];  // [tn][tm][i]
#pragma unroll
    for (int tn = 0; tn < 2; ++tn)
#pragma unroll
      for (int tm = 0; tm < 2; ++tm)
#pragma unroll
        for (int i = 0; i < 4; ++i) {
          float v = acc[tn][tm][i] + bias_r[tn][i];
          if (flag) v += xw_r[tm][tn][i];
          hv[tn][tm][i] = fast_tanh(v);
        }
    if (!last) {
#pragma unroll
      for (int tn = 0; tn < 2; ++tn)
#pragma unroll
        for (int tm = 0; tm < 2; ++tm) {
          unsigned long long pk =
              (unsigned long long)f2bf(hv[tn][tm][0]) |
              ((unsigned long long)f2bf(hv[tn][tm][1]) << 16) |
              ((unsigned long long)f2bf(hv[tn][tm][2]) << 32) |
              ((unsigned long long)f2bf(hv[tn][tm][3]) << 48);
          ushort_t* dst = Hnext + ((size_t)gmv[tm] << 10) + gnb[tn];
          __asm__ __volatile__("global_store_dwordx2 %0, %1, off sc0 sc1"
                               :
                               : "v"(dst), "v"(pk)
                               : "memory");
        }
    } else {
#pragma unroll
      for (int tn = 0; tn < 2; ++tn)
#pragma unroll
        for (int tm = 0; tm < 2; ++tm) {
          float4 o = make_float4(hv[tn][tm][0], hv[tn][tm][1], hv[tn][tm][2],
                                 hv[tn][tm][3]);
          *(float4*)(p.hxout + ((size_t)gmv[tm] << 10) + gnb[tn]) = o;
        }
    }
    // actor partial: sum over this lane's 8 n-positions, reduce over lhi
#pragma unroll
    for (int tm = 0; tm < 2; ++tm) {
      float s = 0.f;
#pragma unroll
      for (int tn = 0; tn < 2; ++tn)
#pragma unroll
        for (int i = 0; i < 4; ++i) s += hv[tn][tm][i] * wa_r[tn][i];
      s += __shfl_xor(s, 16);
      s += __shfl_xor(s, 32);
      if (l < 16) atomicAdd(&p.pacc[(st << 10) + gmv[tm]], s);
    }

    // ---- m-group barrier (16 blocks), no cache maintenance ----
    if (!last) {
      __asm__ __volatile__("s_waitcnt vmcnt(0)" ::: "memory");
      __syncthreads();
      if (t == 0) {
        atomicAdd(mbar, 1u);
        unsigned tgt = (unsigned)(st + 1) << 4;
        while (__hip_atomic_load(mbar, __ATOMIC_RELAXED,
                                 __HIP_MEMORY_SCOPE_AGENT) < tgt)
          __builtin_amdgcn_s_sleep(2);
      }
      __syncthreads();
    }
  }

  gbar(p.barrier, 4, t, bid);
  p.probs[gid] = fast_sigmoid(p.pacc[gid] + p.ba[0]);
}

extern "C" void kernel_launch(void* const* d_in, const int* in_sizes, int n_in,
                              void* d_out, int out_size, void* d_ws,
                              size_t ws_size, hipStream_t stream) {
  char* ws = (char*)d_ws;
  KP p;
  p.x = (const float*)d_in[0];
  p.W1 = (const float*)d_in[1];
  p.b1 = (const float*)d_in[2];
  p.W2 = (const float*)d_in[3];
  p.b2 = (const float*)d_in[4];
  p.Wih = (const float*)d_in[5];
  p.Whh = (const float*)d_in[6];
  p.bih = (const float*)d_in[7];
  p.bhh = (const float*)d_in[8];
  p.Wa = (const float*)d_in[9];
  p.ba = (const float*)d_in[10];
  p.Xb = (ushort_t*)(ws);
  p.W1b = (ushort_t*)(ws + ((size_t)8 << 20));
  p.W2b = (ushort_t*)(ws + ((size_t)16 << 20));
  p.Wihb = (ushort_t*)(ws + ((size_t)18 << 20));
  p.Whhb = (ushort_t*)(ws + ((size_t)20 << 20));
  p.Wsmb = (ushort_t*)(ws + ((size_t)22 << 20));
  p.X1b = (ushort_t*)(ws + ((size_t)24 << 20));
  p.Xlb = (ushort_t*)(ws + ((size_t)26 << 20));
  p.Hb0 = (ushort_t*)(ws + ((size_t)28 << 20));
  p.Hb1 = (ushort_t*)(ws + ((size_t)30 << 20));
  p.xw = (float*)(ws + ((size_t)32 << 20));
  p.bias = (float*)(ws + ((size_t)36 << 20));
  p.pacc = (float*)(ws + ((size_t)36 << 20) + 4096);
  p.barrier = (unsigned*)(ws + ((size_t)36 << 20) + 4096 + 262144);
  p.probs = (float*)d_out;
  p.hxout = (float*)d_out + 65536;

  hipFuncSetAttribute((const void*)fused_rnn,
                      hipFuncAttributeMaxDynamicSharedMemorySize, 155648);
  void* args[] = {&p};
  hipLaunchCooperativeKernel((const void*)fused_rnn, dim3(256), dim3(256),
                             args, 155648, stream);
}